// Round 4
// baseline (229.958 us; speedup 1.0000x reference)
//
#include <hip/hip_runtime.h>
#include <hip/hip_bf16.h>
#include <stdint.h>
#include <stddef.h>

#define D_MODEL 2048
#define NOUT    2048      // SLOTS * D_FIELD
#define BATCH   2
#define SEQ     4096
#define M_TOTAL (BATCH*SEQ)   // 8192
#define SLOTS   8
#define D_FIELD 256
#define CHUNK   64
#define NCHUNK  (SEQ/CHUNK)   // 64

typedef __attribute__((ext_vector_type(4))) float  floatx4;
typedef __attribute__((ext_vector_type(8))) __bf16 bf16x8;
typedef __attribute__((ext_vector_type(4))) __bf16 bf16x4;

// ---------------------------------------------------------------------------
// async global -> LDS, 16B per lane. LDS dest must be wave-uniform base + lane*16.
__device__ __forceinline__ void async_copy16(const void* gsrc, void* ldst) {
  __builtin_amdgcn_global_load_lds(
      (__attribute__((address_space(1))) const void*)(uintptr_t)gsrc,
      (__attribute__((address_space(3))) void*)(uintptr_t)ldst,
      16, 0, 0);
}

// ---------------------------------------------------------------------------
// Kernel 1: cast x and W fp32 -> bf16 into workspace. 4 elems / thread.
__global__ void cast_kernel(const float* __restrict__ x,
                            const float* __restrict__ W,
                            __bf16* __restrict__ xb,
                            __bf16* __restrict__ wb) {
  const long long nx = (long long)M_TOTAL * D_MODEL;  // 16777216
  const long long nw = (long long)NOUT * D_MODEL;     // 4194304
  long long base = ((long long)blockIdx.x * blockDim.x + threadIdx.x) * 4;
  if (base < nx) {
    float4 v = *(const float4*)(x + base);
    bf16x4 o;
    o[0] = (__bf16)v.x; o[1] = (__bf16)v.y; o[2] = (__bf16)v.z; o[3] = (__bf16)v.w;
    *(bf16x4*)(xb + base) = o;
  } else {
    long long j = base - nx;
    if (j < nw) {
      float4 v = *(const float4*)(W + j);
      bf16x4 o;
      o[0] = (__bf16)v.x; o[1] = (__bf16)v.y; o[2] = (__bf16)v.z; o[3] = (__bf16)v.w;
      *(bf16x4*)(wb + j) = o;
    }
  }
}

// ---------------------------------------------------------------------------
// Kernel 2: C[M,N] = Xbf16[M,K] * W[N,K]^T + bias, fused per-chunk carry (scan P1).
// 128x128 tile, BK=64, XOR-swizzled LDS (conflict-free, verified R2: 0 conflicts).
// Grid m-fast: the 16 blocks sharing an A-tile land on one XCD (FETCH 139->66MB,
// verified R3).
__global__ __launch_bounds__(256) void gemm_scan_kernel(
    const __bf16* __restrict__ A,    // [M_TOTAL, D_MODEL]
    const __bf16* __restrict__ Bw,   // [NOUT, D_MODEL]
    const float*  __restrict__ bias, // [NOUT]
    const float*  __restrict__ alphas,
    float* __restrict__ C,           // [M_TOTAL, NOUT]
    float* __restrict__ carry) {     // [BATCH, NCHUNK, NOUT]
  __shared__ __align__(16) __bf16 sA[128 * 64];
  __shared__ __align__(16) __bf16 sB[128 * 64];

  const int t    = threadIdx.x;
  const int lane = t & 63;
  const int wave = t >> 6;
  const int wM   = wave >> 1;
  const int wN   = wave & 1;
  const int m0   = blockIdx.x * 128;   // m fast -> A-tile pinned per XCD
  const int n0   = blockIdx.y * 128;
  const int K    = D_MODEL;

  // staging: thread t covers LDS row r0 = t>>3 (+32 per issue), slot t&7.
  // swizzle: LDS slot s of row r holds k-group g = s ^ (r&7).
  const int r0 = t >> 3;
  const int g  = (t & 7) ^ (r0 & 7);
  const __bf16* gA = A  + (size_t)(m0 + r0) * K + g * 8;
  const __bf16* gB = Bw + (size_t)(n0 + r0) * K + g * 8;
  __bf16* lA = sA + t * 8;
  __bf16* lB = sB + t * 8;

  const int q = lane >> 4;       // quad 0..3
  const int L = lane & 15;       // row-in-16
  const int xorL = L & 7;
  const __bf16* fA = sA + (wM * 64 + L) * 64;
  const __bf16* fB = sB + (wN * 64 + L) * 64;

  floatx4 acc[4][4] = {};

  for (int kt = 0; kt < K; kt += 64) {
    __syncthreads();
#pragma unroll
    for (int i = 0; i < 4; ++i) {
      async_copy16(gA + kt + (size_t)i * 32 * K, lA + i * 2048);
      async_copy16(gB + kt + (size_t)i * 32 * K, lB + i * 2048);
    }
    __syncthreads();   // vmcnt(0) drain
#pragma unroll
    for (int kk = 0; kk < 2; ++kk) {
      const int slot = (((kk * 4 + q) ^ xorL)) * 8;
      bf16x8 af[4], bfr[4];
#pragma unroll
      for (int mi = 0; mi < 4; ++mi) af[mi]  = *(const bf16x8*)(fA + mi * 1024 + slot);
#pragma unroll
      for (int ni = 0; ni < 4; ++ni) bfr[ni] = *(const bf16x8*)(fB + ni * 1024 + slot);
#pragma unroll
      for (int mi = 0; mi < 4; ++mi)
#pragma unroll
        for (int ni = 0; ni < 4; ++ni)
          acc[mi][ni] = __builtin_amdgcn_mfma_f32_16x16x32_bf16(
              af[mi], bfr[ni], acc[mi][ni], 0, 0, 0);
    }
  }

  // ---- epilogue: write C (+bias) and fused per-chunk carry ----
  // C/D layout: col = L, row = q*4 + reg. Wave row-block = one 64-row chunk.
  const int mBase = m0 + wM * 64 + q * 4;
  const int nBase = n0 + wN * 64 + L;
  const float alpha = alphas[(n0 + wN * 64) >> 8];
  const float a4  = (alpha * alpha) * (alpha * alpha);
  const float a16 = (a4 * a4) * (a4 * a4);
  float aq = 1.f;                       // alpha^(12-4q)
#pragma unroll
  for (int i = 0; i < 3; ++i) if (i < 3 - q) aq *= a4;
  const int gm0 = m0 + wM * 64;
  const int bb  = gm0 >> 12;            // / SEQ
  const int jj  = (gm0 & (SEQ - 1)) >> 6;

#pragma unroll
  for (int ni = 0; ni < 4; ++ni) {
    const int n = nBase + ni * 16;
    const float bv = bias[n];
    float tmi[4];
#pragma unroll
    for (int mi = 0; mi < 4; ++mi) {
      const int m = mBase + mi * 16;
      float u[4];
#pragma unroll
      for (int r = 0; r < 4; ++r) {
        u[r] = acc[mi][ni][r] + bv;
        C[(size_t)(m + r) * NOUT + n] = u[r];
      }
      tmi[mi] = ((u[0] * alpha + u[1]) * alpha + u[2]) * alpha + u[3];
    }
    float s = ((tmi[0] * a16 + tmi[1]) * a16 + tmi[2]) * a16 + tmi[3];
    s *= aq;
    s += __shfl_xor(s, 16, 64);
    s += __shfl_xor(s, 32, 64);
    if (q == 0)
      carry[(size_t)(bb * NCHUNK + jj) * NOUT + n] = s;
  }
}

// ---------------------------------------------------------------------------
// Kernel 3 (P2): scan carries across chunks per column, multiplier alpha^CHUNK.
// Wave-parallel Kogge-Stone: one wave per (b,c); lane j = chunk j. 6 shfl steps.
__global__ __launch_bounds__(256) void scan_p2(const float* __restrict__ alphas,
                                               float* __restrict__ carry) {
  const int w    = blockIdx.x * 4 + (threadIdx.x >> 6);  // wave id [0, 4096)
  const int lane = threadIdx.x & 63;                     // chunk index j
  const int c    = w & (NOUT - 1);
  const int b    = w >> 11;
  const float alpha = alphas[c >> 8];
  float a64 = alpha;
#pragma unroll
  for (int i = 0; i < 6; ++i) a64 = a64 * a64;   // alpha^64

  float* p = carry + ((size_t)(b * NCHUNK + lane)) * NOUT + c;
  float v = *p;
  float m = a64;
#pragma unroll
  for (int step = 1; step < 64; step <<= 1) {
    float o = __shfl_up(v, step, 64);
    if (lane >= step) v += m * o;
    m = m * m;
  }
  *p = v;
}

// ---------------------------------------------------------------------------
// Kernel 4 (P3): apply carry-in, rewrite chunk in place. SCALAR, 1 col/thread:
// 512K threads / 2048 blocks -> 8 blocks/CU, full occupancy, coalesced 4B/lane.
// (R2's float4 version collapsed this to 256 blocks = 1 wave/CU on a serial
// 64-deep chain — the hidden ~90us dispatch. Do not re-vectorize.)
__global__ void scan_p3(float* __restrict__ U,
                        const float* __restrict__ alphas,
                        const float* __restrict__ carry) {
  const int idx  = blockIdx.x * blockDim.x + threadIdx.x;  // [0, 2*64*2048)
  const int c    = idx & (NOUT - 1);
  const int rest = idx >> 11;
  const int j    = rest & (NCHUNK - 1);
  const int b    = rest >> 6;
  const float alpha = alphas[c >> 8];
  float s = (j == 0) ? 0.f
                     : carry[(size_t)(b * NCHUNK + (j - 1)) * NOUT + c];
  float* p = U + ((size_t)(b * SEQ + j * CHUNK) * NOUT) + c;
#pragma unroll 8
  for (int tt = 0; tt < CHUNK; ++tt) {
    const float v = alpha * s + p[(size_t)tt * NOUT];
    p[(size_t)tt * NOUT] = v;
    s = v;
  }
}

// ---------------------------------------------------------------------------
extern "C" void kernel_launch(void* const* d_in, const int* in_sizes, int n_in,
                              void* d_out, int out_size, void* d_ws, size_t ws_size,
                              hipStream_t stream) {
  const float* x      = (const float*)d_in[0];
  const float* W      = (const float*)d_in[1];
  const float* bias   = (const float*)d_in[2];
  const float* alphas = (const float*)d_in[3];
  float* out = (float*)d_out;

  // workspace layout (bytes): xb 33,554,432 | wb 8,388,608 | carry 1,048,576
  __bf16* xb   = (__bf16*)d_ws;
  __bf16* wb   = (__bf16*)((char*)d_ws + (size_t)M_TOTAL * D_MODEL * 2);
  float* carry = (float*)((char*)d_ws + (size_t)M_TOTAL * D_MODEL * 2
                                       + (size_t)NOUT * D_MODEL * 2);

  // 1) cast fp32 -> bf16
  {
    const long long total = ((long long)M_TOTAL * D_MODEL + (long long)NOUT * D_MODEL) / 4;
    const int blocks = (int)((total + 255) / 256);  // 20480
    cast_kernel<<<blocks, 256, 0, stream>>>(x, W, xb, wb);
  }
  // 2) projection GEMM + bias -> d_out, fused per-chunk carries -> ws
  {
    dim3 grid(M_TOTAL / 128, NOUT / 128);  // (64, 16) — m fast for XCD locality
    gemm_scan_kernel<<<grid, 256, 0, stream>>>(xb, wb, bias, alphas, out, carry);
  }
  // 3) chunk-carry scan + apply, in place on d_out
  scan_p2<<<(BATCH * NOUT) / 4, 256, 0, stream>>>(alphas, carry);
  scan_p3<<<(BATCH * NCHUNK * NOUT) / 256, 256, 0, stream>>>(out, alphas, carry);
}

// Round 5
// 223.548 us; speedup vs baseline: 1.0287x; 1.0287x over previous
//
#include <hip/hip_runtime.h>
#include <hip/hip_bf16.h>
#include <stdint.h>
#include <stddef.h>

#define D_MODEL 2048
#define NOUT    2048      // SLOTS * D_FIELD
#define BATCH   2
#define SEQ     4096
#define M_TOTAL (BATCH*SEQ)   // 8192
#define SLOTS   8
#define D_FIELD 256
#define CHUNK   64
#define NCHUNK  (SEQ/CHUNK)   // 64

typedef __attribute__((ext_vector_type(4))) float  floatx4;
typedef __attribute__((ext_vector_type(8))) __bf16 bf16x8;
typedef __attribute__((ext_vector_type(4))) __bf16 bf16x4;

// ---------------------------------------------------------------------------
// async global -> LDS, 16B per lane. LDS dest must be wave-uniform base + lane*16.
__device__ __forceinline__ void async_copy16(const void* gsrc, void* ldst) {
  __builtin_amdgcn_global_load_lds(
      (__attribute__((address_space(1))) const void*)(uintptr_t)gsrc,
      (__attribute__((address_space(3))) void*)(uintptr_t)ldst,
      16, 0, 0);
}

// ---------------------------------------------------------------------------
// Kernel 1: cast x and W fp32 -> bf16 into workspace. 4 elems / thread.
__global__ void cast_kernel(const float* __restrict__ x,
                            const float* __restrict__ W,
                            __bf16* __restrict__ xb,
                            __bf16* __restrict__ wb) {
  const long long nx = (long long)M_TOTAL * D_MODEL;  // 16777216
  const long long nw = (long long)NOUT * D_MODEL;     // 4194304
  long long base = ((long long)blockIdx.x * blockDim.x + threadIdx.x) * 4;
  if (base < nx) {
    float4 v = *(const float4*)(x + base);
    bf16x4 o;
    o[0] = (__bf16)v.x; o[1] = (__bf16)v.y; o[2] = (__bf16)v.z; o[3] = (__bf16)v.w;
    *(bf16x4*)(xb + base) = o;
  } else {
    long long j = base - nx;
    if (j < nw) {
      float4 v = *(const float4*)(W + j);
      bf16x4 o;
      o[0] = (__bf16)v.x; o[1] = (__bf16)v.y; o[2] = (__bf16)v.z; o[3] = (__bf16)v.w;
      *(bf16x4*)(wb + j) = o;
    }
  }
}

// ---------------------------------------------------------------------------
// Kernel 2: C[M,N] = Xbf16[M,K] * W[N,K]^T + bias, fused per-chunk carry (scan P1).
// 128x128 tile, BK=64, XOR-swizzled LDS (conflict-free, verified R2: 0 conflicts).
// Grid m-fast: the 16 blocks sharing an A-tile land on one XCD (FETCH 139->66MB,
// verified R3). UNCHANGED from R4 (control).
__global__ __launch_bounds__(256) void gemm_scan_kernel(
    const __bf16* __restrict__ A,    // [M_TOTAL, D_MODEL]
    const __bf16* __restrict__ Bw,   // [NOUT, D_MODEL]
    const float*  __restrict__ bias, // [NOUT]
    const float*  __restrict__ alphas,
    float* __restrict__ C,           // [M_TOTAL, NOUT]
    float* __restrict__ carry) {     // [BATCH, NCHUNK, NOUT] (raw chunk carries)
  __shared__ __align__(16) __bf16 sA[128 * 64];
  __shared__ __align__(16) __bf16 sB[128 * 64];

  const int t    = threadIdx.x;
  const int lane = t & 63;
  const int wave = t >> 6;
  const int wM   = wave >> 1;
  const int wN   = wave & 1;
  const int m0   = blockIdx.x * 128;   // m fast -> A-tile pinned per XCD
  const int n0   = blockIdx.y * 128;
  const int K    = D_MODEL;

  // staging: thread t covers LDS row r0 = t>>3 (+32 per issue), slot t&7.
  // swizzle: LDS slot s of row r holds k-group g = s ^ (r&7).
  const int r0 = t >> 3;
  const int g  = (t & 7) ^ (r0 & 7);
  const __bf16* gA = A  + (size_t)(m0 + r0) * K + g * 8;
  const __bf16* gB = Bw + (size_t)(n0 + r0) * K + g * 8;
  __bf16* lA = sA + t * 8;
  __bf16* lB = sB + t * 8;

  const int q = lane >> 4;       // quad 0..3
  const int L = lane & 15;       // row-in-16
  const int xorL = L & 7;
  const __bf16* fA = sA + (wM * 64 + L) * 64;
  const __bf16* fB = sB + (wN * 64 + L) * 64;

  floatx4 acc[4][4] = {};

  for (int kt = 0; kt < K; kt += 64) {
    __syncthreads();
#pragma unroll
    for (int i = 0; i < 4; ++i) {
      async_copy16(gA + kt + (size_t)i * 32 * K, lA + i * 2048);
      async_copy16(gB + kt + (size_t)i * 32 * K, lB + i * 2048);
    }
    __syncthreads();   // vmcnt(0) drain
#pragma unroll
    for (int kk = 0; kk < 2; ++kk) {
      const int slot = (((kk * 4 + q) ^ xorL)) * 8;
      bf16x8 af[4], bfr[4];
#pragma unroll
      for (int mi = 0; mi < 4; ++mi) af[mi]  = *(const bf16x8*)(fA + mi * 1024 + slot);
#pragma unroll
      for (int ni = 0; ni < 4; ++ni) bfr[ni] = *(const bf16x8*)(fB + ni * 1024 + slot);
#pragma unroll
      for (int mi = 0; mi < 4; ++mi)
#pragma unroll
        for (int ni = 0; ni < 4; ++ni)
          acc[mi][ni] = __builtin_amdgcn_mfma_f32_16x16x32_bf16(
              af[mi], bfr[ni], acc[mi][ni], 0, 0, 0);
    }
  }

  // ---- epilogue: write C (+bias) and fused per-chunk carry ----
  // C/D layout: col = L, row = q*4 + reg. Wave row-block = one 64-row chunk.
  const int mBase = m0 + wM * 64 + q * 4;
  const int nBase = n0 + wN * 64 + L;
  const float alpha = alphas[(n0 + wN * 64) >> 8];
  const float a4  = (alpha * alpha) * (alpha * alpha);
  const float a16 = (a4 * a4) * (a4 * a4);
  float aq = 1.f;                       // alpha^(12-4q)
#pragma unroll
  for (int i = 0; i < 3; ++i) if (i < 3 - q) aq *= a4;
  const int gm0 = m0 + wM * 64;
  const int bb  = gm0 >> 12;            // / SEQ
  const int jj  = (gm0 & (SEQ - 1)) >> 6;

#pragma unroll
  for (int ni = 0; ni < 4; ++ni) {
    const int n = nBase + ni * 16;
    const float bv = bias[n];
    float tmi[4];
#pragma unroll
    for (int mi = 0; mi < 4; ++mi) {
      const int m = mBase + mi * 16;
      float u[4];
#pragma unroll
      for (int r = 0; r < 4; ++r) {
        u[r] = acc[mi][ni][r] + bv;
        C[(size_t)(m + r) * NOUT + n] = u[r];
      }
      tmi[mi] = ((u[0] * alpha + u[1]) * alpha + u[2]) * alpha + u[3];
    }
    float s = ((tmi[0] * a16 + tmi[1]) * a16 + tmi[2]) * a16 + tmi[3];
    s *= aq;
    s += __shfl_xor(s, 16, 64);
    s += __shfl_xor(s, 32, 64);
    if (q == 0)
      carry[(size_t)(bb * NCHUNK + jj) * NOUT + n] = s;
  }
}

// ---------------------------------------------------------------------------
// Kernel 3 (P3'): self-scanning apply — replaces the separate p2 dispatch.
// Each thread first Horner-combines the RAW chunk carries j' < j (<=63 coalesced
// 4B loads from the 1MB L2-resident carry buffer; addresses independent of the
// serial chain so they pipeline), then applies the within-chunk recurrence.
// j is block-uniform (2048 columns = 8 blocks per (b,j)) -> no divergence.
__global__ void scan_apply(float* __restrict__ U,
                           const float* __restrict__ alphas,
                           const float* __restrict__ carry) {
  const int idx  = blockIdx.x * blockDim.x + threadIdx.x;  // [0, 2*64*2048)
  const int c    = idx & (NOUT - 1);
  const int rest = idx >> 11;
  const int j    = rest & (NCHUNK - 1);
  const int b    = rest >> 6;
  const float alpha = alphas[c >> 8];
  float a64 = alpha;
#pragma unroll
  for (int i = 0; i < 6; ++i) a64 *= a64;   // alpha^64

  // carry-in = scan of raw chunk carries over j' < j with multiplier alpha^64
  const float* cb = carry + (size_t)b * NCHUNK * NOUT + c;
  float s = 0.f;
#pragma unroll 8
  for (int jp = 0; jp < j; ++jp)
    s = a64 * s + cb[(size_t)jp * NOUT];

  float* p = U + ((size_t)(b * SEQ + j * CHUNK) * NOUT) + c;
#pragma unroll 8
  for (int tt = 0; tt < CHUNK; ++tt) {
    const float v = alpha * s + p[(size_t)tt * NOUT];
    p[(size_t)tt * NOUT] = v;
    s = v;
  }
}

// ---------------------------------------------------------------------------
extern "C" void kernel_launch(void* const* d_in, const int* in_sizes, int n_in,
                              void* d_out, int out_size, void* d_ws, size_t ws_size,
                              hipStream_t stream) {
  const float* x      = (const float*)d_in[0];
  const float* W      = (const float*)d_in[1];
  const float* bias   = (const float*)d_in[2];
  const float* alphas = (const float*)d_in[3];
  float* out = (float*)d_out;

  // workspace layout (bytes): xb 33,554,432 | wb 8,388,608 | carry 1,048,576
  __bf16* xb   = (__bf16*)d_ws;
  __bf16* wb   = (__bf16*)((char*)d_ws + (size_t)M_TOTAL * D_MODEL * 2);
  float* carry = (float*)((char*)d_ws + (size_t)M_TOTAL * D_MODEL * 2
                                       + (size_t)NOUT * D_MODEL * 2);

  // 1) cast fp32 -> bf16
  {
    const long long total = ((long long)M_TOTAL * D_MODEL + (long long)NOUT * D_MODEL) / 4;
    const int blocks = (int)((total + 255) / 256);  // 20480
    cast_kernel<<<blocks, 256, 0, stream>>>(x, W, xb, wb);
  }
  // 2) projection GEMM + bias -> d_out, fused per-chunk carries -> ws
  {
    dim3 grid(M_TOTAL / 128, NOUT / 128);  // (64, 16) — m fast for XCD locality
    gemm_scan_kernel<<<grid, 256, 0, stream>>>(xb, wb, bias, alphas, out, carry);
  }
  // 3) self-scanning carry apply, in place on d_out (no separate p2 dispatch)
  scan_apply<<<(BATCH * NCHUNK * NOUT) / 256, 256, 0, stream>>>(out, alphas, carry);
}